// Round 5
// baseline (63246.210 us; speedup 1.0000x reference)
//
#include <hip/hip_runtime.h>
#include <math.h>

// Problem: SEQ_LEN=512, BATCH=64, INPUT=256, HIDDEN=512. fp32 in/out.
// v6 "nosync": partition by BATCH ONLY. 4 blocks x 16 batch rows; each block
// computes ALL 2048 gates -> recurrence is block-local. ZERO inter-block
// communication (no flags, no polls, no cooperative launch). Weights stream
// from per-XCD L2 (f16, 3MB, converted once into ws).
#define TT 512
#define BB 64
#define II 256
#define HH 512

#define NTHREADS 512        // 8 waves
#define NBLOCKS 4           // 16 batch rows each
#define KPAD 776            // f16 elements per xh row (768 + 8 pad)
#define ROWB (KPAD*2)       // 1552 B per LDS row

typedef _Float16 f16x8 __attribute__((ext_vector_type(8)));
typedef _Float16 f16x4 __attribute__((ext_vector_type(4)));
typedef float    f32x4 __attribute__((ext_vector_type(4)));

__device__ __forceinline__ float sig_(float v)  { return 1.0f / (1.0f + __expf(-v)); }
__device__ __forceinline__ float tanh_(float v) { float e = __expf(2.0f * v); return 1.0f - 2.0f / (e + 1.0f); }

// Barrier draining ONLY lgkmcnt — global loads/stores stay in flight across it.
__device__ __forceinline__ void barrier_lds() {
    __builtin_amdgcn_sched_barrier(0);
    asm volatile("s_waitcnt lgkmcnt(0)" ::: "memory");
    __builtin_amdgcn_s_barrier();
    __builtin_amdgcn_sched_barrier(0);
}

__global__ void __launch_bounds__(NTHREADS, 2)
lstm_nosync(const float* __restrict__ x,
            const float* __restrict__ Wx,
            const float* __restrict__ bx,
            const float* __restrict__ Wh,
            const float* __restrict__ bh,
            float* __restrict__ out,
            _Float16* __restrict__ wsW)   // [128 tiles][24 ksteps][64 lanes][8 f16] = 3 MB
{
    __shared__ __align__(16) _Float16 xh[16 * KPAD];   // [x 512B | h 1024B | pad] per row, 24,832 B
    __shared__ __align__(16) float    biasc[2048];     // combined bias, col-order hu*4+g, 8 KB
    __shared__ __align__(16) float    exch[8][16*20];  // per-wave gate exchange, 10,240 B
    __shared__ __align__(16) float    cst[HH][16];     // c-state [he][be], 32 KB

    const int blk = blockIdx.x;        // 0..3
    const int b0  = blk * 16;
    const int tid = threadIdx.x;
    const int wv  = tid >> 6;          // wave 0..7: owns gate-cols [wv*256, wv*256+256)
    const int L   = tid & 63;
    const int n   = L & 15;            // MFMA row/col within tile
    const int qd  = L >> 4;            // k-octet

    // ================= one-time prepass =================
    // Convert Wx|Wh (f32) -> swizzled f16 in ws. Layout: frag for (tile ti,
    // kstep kc, lane) at ((ti*24+kc)*64 + lane)*16B -> wave reads are
    // lane-linear 1KB chunks, L2-resident. All 4 blocks convert the full set
    // redundantly (identical bytes; racing writes benign; no sync needed).
    for (int u = tid; u < 128 * 24 * 64; u += NTHREADS) {
        int lane = u & 63;
        unsigned rest = (unsigned)u >> 6;      // ti*24 + kc
        int kc = (int)(rest % 24u);
        int ti = (int)(rest / 24u);
        int col = ti * 16 + (lane & 15);       // gate-col, order hu*4+g
        int g = col & 3, hu = col >> 2;
        int k0 = kc * 32 + (lane >> 4) * 8;
        const float* src = (k0 < II)
            ? (Wx + ((size_t)g * HH + hu) * II + k0)
            : (Wh + ((size_t)g * HH + hu) * HH + (k0 - II));
        float4 u0 = ((const float4*)src)[0];
        float4 u1 = ((const float4*)src)[1];
        f16x8 b = { (_Float16)u0.x, (_Float16)u0.y, (_Float16)u0.z, (_Float16)u0.w,
                    (_Float16)u1.x, (_Float16)u1.y, (_Float16)u1.z, (_Float16)u1.w };
        *(f16x8*)((char*)wsW + (size_t)rest * 1024 + lane * 16) = b;
    }
    __threadfence();   // own ws stores -> visible to own loads (drains + L1 inv)

    // Combined bias into LDS (col-order hu*4+g)
    for (int c = tid; c < 2048; c += NTHREADS) {
        int g = c & 3, hu = c >> 2;
        biasc[c] = bx[g * HH + hu] + bh[g * HH + hu];
    }
    // Zero xh (h-part must be 0 at t=0) and c-state
    for (int i = tid; i < 16 * KPAD / 2; i += NTHREADS) ((unsigned*)xh)[i] = 0u;
    for (int i = tid; i < HH * 16; i += NTHREADS) (&cst[0][0])[i] = 0.f;
    __syncthreads();

    // Stage x_0 into x-part
    #pragma unroll
    for (int i = 0; i < 2; ++i) {
        int ch = tid + i * NTHREADS;           // 0..1023
        int row = ch >> 6, pos = ch & 63;
        float4 v = ((const float4*)(x + ((size_t)0 * BB + b0 + row) * II))[pos];
        f16x4 pk = { (_Float16)v.x, (_Float16)v.y, (_Float16)v.z, (_Float16)v.w };
        *(f16x4*)((char*)xh + row * ROWB + pos * 8) = pk;
    }
    __syncthreads();

    // ================= steady state: zero communication =================
    const char* xhA   = (const char*)xh + n * ROWB + qd * 16;   // A-frag base
    const char* wbase = (const char*)wsW + ((size_t)(wv * 16) * 24 * 64 + L) * 16;
    const size_t HSEQ = (size_t)TT * BB * HH;
    const int be = L >> 2, hle = L & 3;

    // Rolling single-buffer for B (weights): prefetch distance = 1 full tile
    // with only 96 VGPRs (each frag reloaded right after its last use).
    f16x8 bf[24];
    #pragma unroll
    for (int kc = 0; kc < 24; ++kc)
        bf[kc] = *(const f16x8*)(wbase + kc * 1024);

    for (int t = 0; t < TT; ++t) {
        // ---- phase A: load A-frags (xh row n, full K=768) into regs; all
        // waves read the same bytes; reused across all 16 N-tiles.
        f16x8 af[24];
        #pragma unroll
        for (int kc = 0; kc < 24; ++kc)
            af[kc] = *(const f16x8*)(xhA + kc * 64);
        barrier_lds();   // A-reads done -> h/x writers below may overwrite

        // ---- issue x_{t+1} global loads early (land during N-loop) ----
        float4 xv0, xv1;
        if (t + 1 < TT) {
            int ch0 = tid, ch1 = tid + NTHREADS;
            xv0 = ((const float4*)(x + ((size_t)(t + 1) * BB + b0 + (ch0 >> 6)) * II))[ch0 & 63];
            xv1 = ((const float4*)(x + ((size_t)(t + 1) * BB + b0 + (ch1 >> 6)) * II))[ch1 & 63];
        }

        // ---- N-loop: 16 tiles/wave; MFMA + rolling B prefetch + epilogue ----
        #pragma unroll
        for (int nt = 0; nt < 16; ++nt) {
            f32x4 a0 = { 0.f, 0.f, 0.f, 0.f };
            f32x4 a1 = { 0.f, 0.f, 0.f, 0.f };
            #pragma unroll
            for (int kc = 0; kc < 24; ++kc) {
                if (kc & 1) a1 = __builtin_amdgcn_mfma_f32_16x16x32_f16(af[kc], bf[kc], a1, 0, 0, 0);
                else        a0 = __builtin_amdgcn_mfma_f32_16x16x32_f16(af[kc], bf[kc], a0, 0, 0, 0);
            }
            // prefetch next tile (nt=15 wraps to tile 0 for the NEXT step;
            // loads stay in flight across the step barrier — wanted)
            {
                const char* nb = wbase + (size_t)((nt + 1) & 15) * 24576;
                #pragma unroll
                for (int kc = 0; kc < 24; ++kc)
                    bf[kc] = *(const f16x8*)(nb + kc * 1024);
            }
            f32x4 acc = a0 + a1;

            // intra-wave exchange (v1-verified layout): C[row=qd*4+r][col=n]
            float* ew = exch[wv];
            asm volatile("" ::: "memory");
            #pragma unroll
            for (int r = 0; r < 4; ++r)
                ew[(qd * 4 + r) * 20 + n] = acc[r];
            float4 pre4 = *(const float4*)&ew[be * 20 + hle * 4];
            asm volatile("" ::: "memory");

            const int ti = wv * 16 + nt;
            const int he = ti * 4 + hle;
            float4 b4 = *(const float4*)&biasc[he * 4];
            float cprev = cst[he][be];
            float fg = sig_(pre4.x + b4.x);
            float ig = sig_(pre4.y + b4.y);
            float og = sig_(pre4.z + b4.z);
            float cn = fg * cprev + ig * tanh_(pre4.w + b4.w);
            float hv = og * tanh_(cn);
            cst[he][be] = cn;

            out[((size_t)t * BB + b0 + be) * HH + he] = hv;
            if (t == TT - 1) {
                size_t r = (size_t)(b0 + be) * HH + he;
                out[HSEQ + r] = hv;                        // h_last
                out[HSEQ + (size_t)BB * HH + r] = cn;      // c_last
            } else {
                // publish h_t straight into the LDS xh tile (recurrence never
                // leaves the CU): pack f16 pairs across hle partner lanes.
                union { _Float16 f; unsigned short u; } cv; cv.f = (_Float16)hv;
                unsigned mine  = cv.u;
                unsigned other = (unsigned)__shfl_xor((int)mine, 1, 64);
                if ((hle & 1) == 0) {
                    unsigned pk = mine | (other << 16);
                    *(unsigned*)((char*)xh + be * ROWB + 512 + he * 2) = pk;
                }
            }
        }

        // ---- write staged x_{t+1} (loads have long landed) ----
        if (t + 1 < TT) {
            int ch0 = tid, ch1 = tid + NTHREADS;
            f16x4 p0 = { (_Float16)xv0.x, (_Float16)xv0.y, (_Float16)xv0.z, (_Float16)xv0.w };
            f16x4 p1 = { (_Float16)xv1.x, (_Float16)xv1.y, (_Float16)xv1.z, (_Float16)xv1.w };
            *(f16x4*)((char*)xh + (ch0 >> 6) * ROWB + (ch0 & 63) * 8) = p0;
            *(f16x4*)((char*)xh + (ch1 >> 6) * ROWB + (ch1 & 63) * 8) = p1;
        }
        barrier_lds();   // h_t + x_{t+1} visible before next phase A
    }
}

extern "C" void kernel_launch(void* const* d_in, const int* in_sizes, int n_in,
                              void* d_out, int out_size, void* d_ws, size_t ws_size,
                              hipStream_t stream)
{
    const float* x  = (const float*)d_in[0];
    const float* Wx = (const float*)d_in[1];
    const float* bx = (const float*)d_in[2];
    const float* Wh = (const float*)d_in[3];
    const float* bh = (const float*)d_in[4];
    float* out = (float*)d_out;

    // ws: [0, 3MB) swizzled f16 weights (requires ws_size >= 3,145,728 B)
    _Float16* wsW = (_Float16*)d_ws;

    hipLaunchKernelGGL(lstm_nosync, dim3(NBLOCKS), dim3(NTHREADS), 0, stream,
                       x, Wx, bx, Wh, bh, out, wsW);
}

// Round 6
// 2080.320 us; speedup vs baseline: 30.4022x; 30.4022x over previous
//
#include <hip/hip_runtime.h>
#include <hip/hip_cooperative_groups.h>
#include <math.h>

namespace cg = cooperative_groups;

// Problem: SEQ_LEN=512, BATCH=64, INPUT=256, HIDDEN=512. fp32 in/out.
// v7 "xcd-local": v1's exact protocol, but 8 groups x 8 blocks with grp = blk&7
// so that (under round-robin dispatch XCD = blk%8) each group's entire
// h-exchange lives on ONE XCD's L2 instead of crossing MALL.
#define TT 512
#define BB 64
#define II 256
#define HH 512

#define NTHREADS 1024       // 16 waves
#define NGRP 8              // batch groups (8 rows each), one per XCD
#define NCB  8              // blocks per group; each owns 64 h-units
#define NBLOCKS (NGRP*NCB)  // 64 blocks

#define KPAD 776            // f16 elements per A row (768 + 8 pad)

typedef _Float16 f16x8 __attribute__((ext_vector_type(8)));
typedef _Float16 f16x4 __attribute__((ext_vector_type(4)));
typedef float    f32x4 __attribute__((ext_vector_type(4)));

__device__ __forceinline__ float sig_(float v)  { return 1.0f / (1.0f + __expf(-v)); }
__device__ __forceinline__ float tanh_(float v) { float e = __expf(2.0f * v); return 1.0f - 2.0f / (e + 1.0f); }

__global__ void __launch_bounds__(NTHREADS, 1)
lstm_xcd(const float* __restrict__ x,
         const float* __restrict__ Wx,
         const float* __restrict__ bx,
         const float* __restrict__ Wh,
         const float* __restrict__ bh,
         float* __restrict__ out,
         unsigned int* __restrict__ flags,   // [NGRP][16] u32: one 64B line per group
         unsigned int* __restrict__ hbuf)    // [2][NGRP][8 rows][256] u32 packed f16 pairs
{
    __shared__ __align__(16) _Float16 AL[16 * KPAD];     // rows 0-7 real, 8-15 zero pad
    __shared__ __align__(16) float    exch[16][8 * 20];  // per-wave, rows 0-7 only

    cg::grid_group grid = cg::this_grid();

    const int blk  = blockIdx.x;
    const int grp  = blk & 7;          // batch group -> XCD (round-robin assumption)
    const int b0   = grp * 8;
    const int ct   = blk >> 3;         // 0..7, h-units [ct*64, ct*64+64)
    const int hblk = ct * 64;

    const int tid = threadIdx.x;
    const int wv  = tid >> 6;          // wave 0..15: h-quad hblk + wv*4
    const int L   = tid & 63;
    const int n   = L & 15;            // MFMA A-row m / B-col n
    const int qd  = L >> 4;            // lane quad -> k = qd*8..qd*8+7

    // ---- Preload B fragments (constant across ALL 512 steps) ----
    // B col n of wave wv: gate g = n&3, h-unit hu = hblk + wv*4 + (n>>2)
    const int g  = n & 3;
    const int hu = hblk + wv * 4 + (n >> 2);
    f16x8 bfr[24];
    #pragma unroll
    for (int kc = 0; kc < 24; ++kc) {
        int k0 = kc * 32 + qd * 8;
        const float* src = (kc < 8)
            ? (Wx + ((size_t)g * HH + hu) * II + k0)
            : (Wh + ((size_t)g * HH + hu) * HH + (k0 - 256));
        float4 u0 = ((const float4*)src)[0];
        float4 u1 = ((const float4*)src)[1];
        f16x8 b = { (_Float16)u0.x, (_Float16)u0.y, (_Float16)u0.z, (_Float16)u0.w,
                    (_Float16)u1.x, (_Float16)u1.y, (_Float16)u1.z, (_Float16)u1.w };
        bfr[kc] = b;
    }

    // Epilogue ownership: lane -> (batch be, h-unit he); only be<8 lanes are real
    const int be  = L >> 2;
    const int hle = L & 3;
    const int he  = hblk + wv * 4 + hle;
    float bias4[4];
    #pragma unroll
    for (int g2 = 0; g2 < 4; ++g2) bias4[g2] = bx[g2 * HH + he] + bh[g2 * HH + he];

    // ---- Zero A tile (pad rows 8-15 stay zero forever), own flag; grid sync ----
    for (int i = tid; i < 16 * KPAD / 2; i += NTHREADS) ((unsigned*)AL)[i] = 0u;
    if (tid == 0)
        __hip_atomic_store(&flags[grp * 16 + ct], 0u,
                           __ATOMIC_RELAXED, __HIP_MEMORY_SCOPE_AGENT);
    grid.sync();

    const size_t HSEQ = (size_t)TT * BB * HH;
    float c_state = 0.0f;
    float* exchW = exch[wv];

    for (int t = 0; t < TT; ++t) {
        // ---- Stage x_t rows 0-7 (512 float4 chunks; no h dependence) ----
        if (tid < 512) {
            int row = tid >> 6, pos = tid & 63;
            float4 v = ((const float4*)(x + ((size_t)t * BB + b0 + row) * II))[pos];
            f16x4 pk = { (_Float16)v.x, (_Float16)v.y, (_Float16)v.z, (_Float16)v.w };
            *(f16x4*)&AL[row * KPAD + pos * 4] = pk;
        }

        // ---- Wave 0 polls the group's 8 flags (one 64B line, XCD-local) ----
        if (t > 0 && wv == 0) {
            const unsigned int* fp = flags + grp * 16;
            const unsigned tu = (unsigned)t;
            for (;;) {
                unsigned f = (L < NCB)
                    ? __hip_atomic_load(&fp[L], __ATOMIC_RELAXED, __HIP_MEMORY_SCOPE_AGENT)
                    : 0xFFFFFFFFu;
                if (__all((int)(f >= tu))) break;
                __builtin_amdgcn_s_sleep(1);
            }
        }
        __syncthreads();   // x staged + h_{t-1} known visible (v1 semantics)

        // ---- Stage h_{t-1} rows 0-7 (1024 x 8B, one per thread, XCD-local) ----
        if (t > 0) {
            const unsigned long long* hsrc = (const unsigned long long*)
                (hbuf + (size_t)((t & 1) * NGRP + grp) * (8 * 256));
            int row = tid >> 7, pos = tid & 127;
            unsigned long long u = __hip_atomic_load(
                hsrc + (size_t)row * 128 + pos,
                __ATOMIC_RELAXED, __HIP_MEMORY_SCOPE_AGENT);
            *(unsigned long long*)((char*)AL + row * (KPAD * 2) + II * 2 + pos * 8) = u;
            __syncthreads();
        }

        // ---- MFMA: full K=768, B from registers, 2 chains ----
        const char* Ab = (const char*)AL + n * (KPAD * 2) + qd * 16;
        f32x4 a0 = { 0.f, 0.f, 0.f, 0.f };
        f32x4 a1 = { 0.f, 0.f, 0.f, 0.f };
        #pragma unroll
        for (int kc = 0; kc < 8; ++kc) {           // x-part
            f16x8 a = *(const f16x8*)(Ab + kc * 64);
            if (kc & 1) a1 = __builtin_amdgcn_mfma_f32_16x16x32_f16(a, bfr[kc], a1, 0, 0, 0);
            else        a0 = __builtin_amdgcn_mfma_f32_16x16x32_f16(a, bfr[kc], a0, 0, 0, 0);
        }
        if (t > 0) {
            #pragma unroll
            for (int kc = 8; kc < 24; ++kc) {      // h-part
                f16x8 a = *(const f16x8*)(Ab + kc * 64);
                if (kc & 1) a1 = __builtin_amdgcn_mfma_f32_16x16x32_f16(a, bfr[kc], a1, 0, 0, 0);
                else        a0 = __builtin_amdgcn_mfma_f32_16x16x32_f16(a, bfr[kc], a0, 0, 0, 0);
            }
        }
        f32x4 acc = a0 + a1;

        // ---- Intra-wave exchange: only real C rows 0-7 (qd<2) ----
        #pragma unroll
        for (int r = 0; r < 4; ++r)
            if (qd < 2) exchW[(qd * 4 + r) * 20 + n] = acc[r];
        // same wave writes then reads: lockstep + in-order DS, no barrier needed
        float4 pre4 = { 0.f, 0.f, 0.f, 0.f };
        if (be < 8) pre4 = *(const float4*)&exchW[be * 20 + hle * 4];

        if (be < 8) {
            // ---- Gates; c_state in-register ----
            float pf = pre4.x + bias4[0];
            float pi = pre4.y + bias4[1];
            float po = pre4.z + bias4[2];
            float pc = pre4.w + bias4[3];
            float fg = sig_(pf), ig = sig_(pi), og = sig_(po);
            float cn = fg * c_state + ig * tanh_(pc);
            float hv = og * tanh_(cn);
            c_state = cn;

            out[((size_t)t * BB + b0 + be) * HH + he] = hv;
            if (t == TT - 1) {
                size_t r = (size_t)(b0 + be) * HH + he;
                out[HSEQ + r] = hv;                        // h_last
                out[HSEQ + (size_t)BB * HH + r] = cn;      // c_last
            }

            // ---- Publish h_t as packed f16 pairs (XCD-local line) ----
            union { _Float16 f; unsigned short u; } cv; cv.f = (_Float16)hv;
            unsigned mine  = cv.u;
            unsigned other = (unsigned)__shfl_xor((int)mine, 1, 64);
            if ((hle & 1) == 0) {
                unsigned pk = mine | (other << 16);
                unsigned int* hdst = hbuf + (size_t)(((t + 1) & 1) * NGRP + grp) * (8 * 256);
                __hip_atomic_store(&hdst[(unsigned)be * 256 + (unsigned)(he >> 1)],
                                   pk, __ATOMIC_RELAXED, __HIP_MEMORY_SCOPE_AGENT);
            }
        }

        // syncthreads drains vmcnt (all waves' h stores at L2) before the flag
        __syncthreads();
        if (t != TT - 1 && tid == 0)
            __hip_atomic_store(&flags[grp * 16 + ct], (unsigned)(t + 1),
                               __ATOMIC_RELAXED, __HIP_MEMORY_SCOPE_AGENT);
    }
}

extern "C" void kernel_launch(void* const* d_in, const int* in_sizes, int n_in,
                              void* d_out, int out_size, void* d_ws, size_t ws_size,
                              hipStream_t stream)
{
    const float* x  = (const float*)d_in[0];
    const float* Wx = (const float*)d_in[1];
    const float* bx = (const float*)d_in[2];
    const float* Wh = (const float*)d_in[3];
    const float* bh = (const float*)d_in[4];
    float* out = (float*)d_out;

    // ws: [0,4KB) per-block epoch flags [NGRP][16]; [4KB, 4KB+64KB) h ping-pong
    unsigned int* flags = (unsigned int*)d_ws;
    unsigned int* hbuf  = (unsigned int*)((char*)d_ws + 4096);

    void* args[] = { (void*)&x, (void*)&Wx, (void*)&bx, (void*)&Wh, (void*)&bh,
                     (void*)&out, (void*)&flags, (void*)&hbuf };
    hipLaunchCooperativeKernel((const void*)lstm_xcd,
                               dim3(NBLOCKS), dim3(NTHREADS),
                               args, 0, stream);
}

// Round 8
// 1994.423 us; speedup vs baseline: 31.7115x; 1.0431x over previous
//
#include <hip/hip_runtime.h>
#include <hip/hip_cooperative_groups.h>
#include <math.h>

namespace cg = cooperative_groups;

// Problem: SEQ_LEN=512, BATCH=64, INPUT=256, HIDDEN=512. fp32 in/out.
// v8 "thin-blocks" (resubmit after infra failure): EXACT v1 protocol
// (3 syncthreads, wave0 flag poll, packed-pair h publish), single variable
// changed vs v1: 128 blocks x 4 waves (was 64 x 8). Per-block serial
// LDS-read work halves; 128 CUs active.
#define TT 512
#define BB 64
#define II 256
#define HH 512

#define NTHREADS 256        // 4 waves
#define NGRP 4              // batch groups (16 rows each)
#define NCT  32             // h-tile blocks per group (16 h-units each)
#define NBLOCKS (NGRP*NCT)  // 128 blocks total

#define KPAD 776            // f16 elements per A row (768 + 8 pad)

typedef _Float16 f16x8 __attribute__((ext_vector_type(8)));
typedef _Float16 f16x4 __attribute__((ext_vector_type(4)));
typedef float    f32x4 __attribute__((ext_vector_type(4)));

__device__ __forceinline__ float sig_(float v)  { return 1.0f / (1.0f + __expf(-v)); }
__device__ __forceinline__ float tanh_(float v) { float e = __expf(2.0f * v); return 1.0f - 2.0f / (e + 1.0f); }

__global__ void __launch_bounds__(NTHREADS, 2)
lstm_thin(const float* __restrict__ x,
          const float* __restrict__ Wx,
          const float* __restrict__ bx,
          const float* __restrict__ Wh,
          const float* __restrict__ bh,
          float* __restrict__ out,
          unsigned int* __restrict__ flags,   // [NGRP][64] u32 (256B per group)
          unsigned int* __restrict__ hbuf)    // [2][BB][256] u32 = packed f16 pairs
{
    __shared__ __align__(16) _Float16 AL[16 * KPAD];     // A = [x_t | h_{t-1}], 24,832 B
    __shared__ __align__(16) float    exch[4 * 16 * 20]; // per-wave gate exchange, 5,120 B

    cg::grid_group grid = cg::this_grid();

    const int blk  = blockIdx.x;
    const int grp  = blk & 3;          // batch group (16 rows)
    const int b0   = grp * 16;
    const int ct   = blk >> 2;         // 0..31, h-units [ct*16, ct*16+16)
    const int hblk = ct * 16;

    const int tid = threadIdx.x;
    const int wv  = tid >> 6;          // wave 0..3: h-quad hblk + wv*4
    const int L   = tid & 63;
    const int n   = L & 15;            // MFMA A-row m / B-col n (lane&15)
    const int qd  = L >> 4;            // lane quad -> k = qd*8..qd*8+7

    // ---- Preload B fragments into registers; constant across ALL 512 steps ----
    // B col n of wave wv: gate g = n&3, h-unit hu = hblk + wv*4 + (n>>2)
    const int g  = n & 3;
    const int hu = hblk + wv * 4 + (n >> 2);
    f16x8 bfr[24];
    #pragma unroll
    for (int kc = 0; kc < 24; ++kc) {
        int k0 = kc * 32 + qd * 8;     // kc<8 entirely in x-part, kc>=8 in h-part
        const float* src = (kc < 8)
            ? (Wx + ((size_t)g * HH + hu) * II + k0)
            : (Wh + ((size_t)g * HH + hu) * HH + (k0 - 256));
        float4 u0 = ((const float4*)src)[0];
        float4 u1 = ((const float4*)src)[1];
        f16x8 b = { (_Float16)u0.x, (_Float16)u0.y, (_Float16)u0.z, (_Float16)u0.w,
                    (_Float16)u1.x, (_Float16)u1.y, (_Float16)u1.z, (_Float16)u1.w };
        bfr[kc] = b;
    }

    // Epilogue ownership: lane -> (batch be, h-unit he); c_state lives here forever
    const int be  = L >> 2;
    const int hle = L & 3;
    const int he  = hblk + wv * 4 + hle;
    float bias4[4];
    #pragma unroll
    for (int g2 = 0; g2 < 4; ++g2) bias4[g2] = bx[g2 * HH + he] + bh[g2 * HH + he];

    // ---- Zero own flag, then the single full-grid sync ----
    if (tid == 0)
        __hip_atomic_store(&flags[grp * 64 + ct], 0u,
                           __ATOMIC_RELAXED, __HIP_MEMORY_SCOPE_AGENT);
    grid.sync();

    const size_t HSEQ = (size_t)TT * BB * HH;
    float c_state = 0.0f;
    float* exchW = &exch[wv * 16 * 20];

    for (int t = 0; t < TT; ++t) {
        // ---- Stage x_t (no dependence on h: happens before/while polling) ----
        #pragma unroll
        for (int i = 0; i < 4; ++i) {
            int ch = tid + i * NTHREADS;           // 0..1023
            int row = ch >> 6, pos = ch & 63;
            float4 v = ((const float4*)(x + ((size_t)t * BB + b0 + row) * II))[pos];
            f16x4 p = { (_Float16)v.x, (_Float16)v.y, (_Float16)v.z, (_Float16)v.w };
            *(f16x4*)&AL[row * KPAD + pos * 4] = p;
        }

        // ---- Wave 0 polls the 32 group flags (independent producer stores) ----
        if (t > 0 && wv == 0) {
            const unsigned int* fp = flags + grp * 64;
            for (;;) {
                unsigned f = (L < NCT)
                    ? __hip_atomic_load(&fp[L], __ATOMIC_RELAXED, __HIP_MEMORY_SCOPE_AGENT)
                    : 0xFFFFFFFFu;
                if (__all((int)(f >= (unsigned)t))) break;
                __builtin_amdgcn_s_sleep(1);
            }
        }
        __syncthreads();   // x staged + h_{t-1} known visible

        // ---- Stage h_{t-1} rows b0..b0+15 (8 x 8B per thread) ----
        if (t > 0) {
            const unsigned long long* hsrc =
                (const unsigned long long*)(hbuf + (size_t)(t & 1) * (BB * 256));
            #pragma unroll
            for (int i = 0; i < 8; ++i) {
                int ch = tid + i * NTHREADS;       // 0..2047
                int row = ch >> 7, pos = ch & 127;
                unsigned long long u = __hip_atomic_load(
                    hsrc + (size_t)(b0 + row) * 128 + pos,
                    __ATOMIC_RELAXED, __HIP_MEMORY_SCOPE_AGENT);
                *(unsigned long long*)((char*)AL + row * (KPAD * 2) + II * 2 + pos * 8) = u;
            }
            __syncthreads();
        }

        // ---- MFMA: full K=768 per wave, B from registers, no K-split ----
        const char* Ab = (const char*)AL + n * (KPAD * 2) + qd * 16;
        f32x4 acc = { 0.f, 0.f, 0.f, 0.f };
        #pragma unroll
        for (int kc = 0; kc < 8; ++kc) {           // x-part
            f16x8 a = *(const f16x8*)(Ab + kc * 64);
            acc = __builtin_amdgcn_mfma_f32_16x16x32_f16(a, bfr[kc], acc, 0, 0, 0);
        }
        if (t > 0) {
            #pragma unroll
            for (int kc = 8; kc < 24; ++kc) {      // h-part
                f16x8 a = *(const f16x8*)(Ab + kc * 64);
                acc = __builtin_amdgcn_mfma_f32_16x16x32_f16(a, bfr[kc], acc, 0, 0, 0);
            }
        }

        // ---- Intra-wave exchange: C[row=qd*4+r][col=n] -> gates per (b,h) ----
        #pragma unroll
        for (int r = 0; r < 4; ++r)
            exchW[(qd * 4 + r) * 20 + n] = acc[r];
        // same wave writes then reads: lockstep, no barrier needed
        float4 pre4 = *(const float4*)&exchW[be * 20 + hle * 4];

        // ---- Gates; c_state in-register ----
        float pf = pre4.x + bias4[0];
        float pi = pre4.y + bias4[1];
        float po = pre4.z + bias4[2];
        float pc = pre4.w + bias4[3];
        float fg = sig_(pf), ig = sig_(pi), og = sig_(po);
        float cn = fg * c_state + ig * tanh_(pc);
        float hv = og * tanh_(cn);
        c_state = cn;

        out[((size_t)t * BB + b0 + be) * HH + he] = hv;
        if (t == TT - 1) {
            size_t r = (size_t)(b0 + be) * HH + he;
            out[HSEQ + r] = hv;                        // h_last
            out[HSEQ + (size_t)BB * HH + r] = cn;      // c_last
        }

        // ---- Publish h_t as packed f16 pairs ----
        {
            union { _Float16 f; unsigned short u; } cv; cv.f = (_Float16)hv;
            unsigned mine  = cv.u;
            unsigned other = (unsigned)__shfl_xor((int)mine, 1, 64);
            if ((hle & 1) == 0) {
                unsigned pk = mine | (other << 16);
                unsigned int* hdst = hbuf + (size_t)((t + 1) & 1) * (BB * 256);
                __hip_atomic_store(&hdst[(unsigned)(b0 + be) * 256 + (unsigned)(he >> 1)],
                                   pk, __ATOMIC_RELAXED, __HIP_MEMORY_SCOPE_AGENT);
            }
        }

        // syncthreads drains vmcnt (all waves' h stores at L3) before the flag
        __syncthreads();
        if (t != TT - 1 && tid == 0)
            __hip_atomic_store(&flags[grp * 64 + ct], (unsigned)(t + 1),
                               __ATOMIC_RELAXED, __HIP_MEMORY_SCOPE_AGENT);
    }
}

extern "C" void kernel_launch(void* const* d_in, const int* in_sizes, int n_in,
                              void* d_out, int out_size, void* d_ws, size_t ws_size,
                              hipStream_t stream)
{
    const float* x  = (const float*)d_in[0];
    const float* Wx = (const float*)d_in[1];
    const float* bx = (const float*)d_in[2];
    const float* Wh = (const float*)d_in[3];
    const float* bh = (const float*)d_in[4];
    float* out = (float*)d_out;

    // ws: [0,4KB) epoch flags; [4KB, 4KB+128KB) h f16-pair ping-pong
    unsigned int* flags = (unsigned int*)d_ws;
    unsigned int* hbuf  = (unsigned int*)((char*)d_ws + 4096);

    void* args[] = { (void*)&x, (void*)&Wx, (void*)&bx, (void*)&Wh, (void*)&bh,
                     (void*)&out, (void*)&flags, (void*)&hbuf };
    hipLaunchCooperativeKernel((const void*)lstm_thin,
                               dim3(NBLOCKS), dim3(NTHREADS),
                               args, 0, stream);
}